// Round 15
// baseline (388.753 us; speedup 1.0000x reference)
//
#include <hip/hip_runtime.h>
#include <hip/hip_fp16.h>
#include <math.h>

#define N_NODES 100000
#define NC 391               // ceil(N_NODES/256) coarse buckets (256 nodes each)
#define NBLK64 1563          // ceil(N_NODES/64)
#define BN_EPS 1e-5f
#define PART_BLOCKS 128

typedef _Float16 half4v __attribute__((ext_vector_type(4)));
typedef float f32x4 __attribute__((ext_vector_type(4)));

// ---------------------------------------------------------------------------
__global__ void zero_misc_k(float* stats, int* gcnt) {
    int gid = blockIdx.x * blockDim.x + threadIdx.x;
    if (gid < 384) stats[gid] = 0.f;
    if (gid < NC) gcnt[gid] = 0;
}

// x fp32 -> fp16 (4 elems per thread)
__global__ void tofp16_k(const float* __restrict__ x, __half* __restrict__ xh, int n4) {
    int gid = blockIdx.x * blockDim.x + threadIdx.x;
    if (gid >= n4) return;
    float4 v = reinterpret_cast<const float4*>(x)[gid];
    union { float2 f; __half2 h[2]; } u;
    u.h[0] = __float22half2_rn(make_float2(v.x, v.y));
    u.h[1] = __float22half2_rn(make_float2(v.z, v.w));
    reinterpret_cast<float2*>(xh)[gid] = u.f;
}

// transpose + fp16-convert the six 64x64 MLP weights: Wt[c][k] = fp16(W[k][c])
__global__ void wtr_k(const float* w0, const float* w1, const float* w2,
                      const float* w3, const float* w4, const float* w5,
                      _Float16* wth) {
    const float* src[6] = {w0, w1, w2, w3, w4, w5};
    const float* W = src[blockIdx.x];
    _Float16* D = wth + (size_t)blockIdx.x * 4096;
    for (int idx = threadIdx.x; idx < 4096; idx += 256) {
        int k = idx >> 6, c = idx & 63;
        D[c * 64 + k] = (_Float16)W[idx];
    }
}

// coarse histogram: bucket = dst >> 8
__global__ __launch_bounds__(256) void histC_k(const int* __restrict__ ei,
                                               int* __restrict__ gcnt, int E) {
    __shared__ int cnt[NC];
    for (int i = threadIdx.x; i < NC; i += 256) cnt[i] = 0;
    __syncthreads();
    int per = (E + gridDim.x - 1) / gridDim.x;
    int s0 = blockIdx.x * per, s1 = min(E, s0 + per);
    for (int e = s0 + threadIdx.x; e < s1; e += 256)
        atomicAdd(&cnt[ei[E + e] >> 8], 1);
    __syncthreads();
    for (int i = threadIdx.x; i < NC; i += 256)
        if (cnt[i]) atomicAdd(&gcnt[i], cnt[i]);
}

// exclusive scan of NC coarse counts (single block, 2 elems/thread)
__global__ __launch_bounds__(256) void scanC_k(const int* __restrict__ gcnt,
                                               int* __restrict__ cbase,
                                               int* __restrict__ gcursor) {
    __shared__ int tmp[256];
    int t = threadIdx.x;
    int v0 = (2 * t < NC) ? gcnt[2 * t] : 0;
    int v1 = (2 * t + 1 < NC) ? gcnt[2 * t + 1] : 0;
    int s = v0 + v1;
    tmp[t] = s;
    __syncthreads();
    for (int off = 1; off < 256; off <<= 1) {
        int a = (t >= off) ? tmp[t - off] : 0;
        __syncthreads();
        tmp[t] += a;
        __syncthreads();
    }
    int run = tmp[t] - s;
    if (2 * t < NC) { cbase[2 * t] = run; gcursor[2 * t] = run; }
    run += v0;
    if (2 * t + 1 < NC) { cbase[2 * t + 1] = run; gcursor[2 * t + 1] = run; }
    if (t == 255) cbase[NC] = tmp[255];  // == E
}

// coarse partition: part[] entries = (dst&255)<<17 | src, coarse-contiguous.
__global__ __launch_bounds__(256) void partC_k(const int* __restrict__ ei,
                                               int* __restrict__ gcursor,
                                               int* __restrict__ part, int E) {
    __shared__ int cnt[NC];
    __shared__ int base[NC];
    for (int i = threadIdx.x; i < NC; i += 256) cnt[i] = 0;
    __syncthreads();
    int per = (E + gridDim.x - 1) / gridDim.x;
    int s0 = blockIdx.x * per, s1 = min(E, s0 + per);
    for (int e = s0 + threadIdx.x; e < s1; e += 256)
        atomicAdd(&cnt[ei[E + e] >> 8], 1);
    __syncthreads();
    for (int i = threadIdx.x; i < NC; i += 256) {
        int c = cnt[i];
        base[i] = c ? atomicAdd(&gcursor[i], c) : 0;
    }
    __syncthreads();
    for (int i = threadIdx.x; i < NC; i += 256) cnt[i] = 0;
    __syncthreads();
    for (int e = s0 + threadIdx.x; e < s1; e += 256) {
        int s = ei[e], d = ei[E + e];
        int b = d >> 8, dl = d & 255;
        int lo = atomicAdd(&cnt[b], 1);
        part[base[b] + lo] = (dl << 17) | s;
    }
}

// per-coarse-bucket counting sort -> row_ptr + node-ordered csr_src.
__global__ __launch_bounds__(256) void csrD_k(const int* __restrict__ part,
                                              const int* __restrict__ cbase,
                                              int* __restrict__ row_ptr,
                                              int* __restrict__ csr_src) {
    __shared__ int cnt[256];
    __shared__ int tmp[256];
    __shared__ int cur[256];
    int b = blockIdx.x;
    int t = threadIdx.x;
    int e0 = cbase[b], e1 = cbase[b + 1];
    cnt[t] = 0;
    __syncthreads();
    for (int i = e0 + t; i < e1; i += 256) atomicAdd(&cnt[(part[i] >> 17) & 255], 1);
    __syncthreads();
    int c = cnt[t];
    tmp[t] = c;
    __syncthreads();
    for (int off = 1; off < 256; off <<= 1) {
        int a = (t >= off) ? tmp[t - off] : 0;
        __syncthreads();
        tmp[t] += a;
        __syncthreads();
    }
    int excl = tmp[t] - c;
    int node = b * 256 + t;
    if (node < N_NODES) row_ptr[node] = e0 + excl;
    cur[t] = e0 + excl;
    __syncthreads();
    for (int i = e0 + t; i < e1; i += 256) {
        int u = part[i];
        int dl = (u >> 17) & 255;
        int pos = atomicAdd(&cur[dl], 1);
        csr_src[pos] = u & 0x1FFFF;
    }
    if (b == NC - 1 && t == 0) row_ptr[N_NODES] = cbase[NC];
}

// ---------------------------------------------------------------------------
// Fused GIN layer: block = 64 nodes, 256 threads, ~9.7 KB LDS.
// Phase A: register gather (pre-activated fp16 rows, 16-deep load pipeline) -> xs.
// Phase B: MFMA MLP (v_mfma_f32_16x16x16_f16), h1 per-wave in xs; store + stats.
__global__ __launch_bounds__(256) void layer_k(
    const __half* __restrict__ hin,
    const int* __restrict__ row_ptr, const int* __restrict__ csr_src,
    const float* __restrict__ epsp,
    const _Float16* __restrict__ wt1, const float* __restrict__ b1,
    const _Float16* __restrict__ wt2, const float* __restrict__ b2,
    __half* __restrict__ hout, float* __restrict__ stats) {
    __shared__ _Float16 xs[64][72];     // row-major gathered tile / h1 / h buffer
    __shared__ float sred[128];

    int tid = threadIdx.x;
    int r0 = blockIdx.x * 64;
    if (tid < 128) sred[tid] = 0.f;

    float eps1 = 1.0f + *epsp;
    int cg = tid & 15, lg = tid >> 4;
    union F2H { float2 f; __half2 h[2]; };

    // ---- Phase A: gather, 16 lanes/node, 4 node-passes, 16-deep pipeline ----
#pragma unroll
    for (int i = 0; i < 4; ++i) {
        int rloc = lg + i * 16;
        int node = r0 + rloc;
        float4 acc = make_float4(0.f, 0.f, 0.f, 0.f);
        if (node < N_NODES) {
            F2H sv;
            sv.f = reinterpret_cast<const float2*>(hin + (size_t)node * 64)[cg];
            float2 f0 = __half22float2(sv.h[0]);
            float2 f1 = __half22float2(sv.h[1]);
            acc = make_float4(f0.x * eps1, f0.y * eps1, f1.x * eps1, f1.y * eps1);
            int j0 = row_ptr[node], j1 = row_ptr[node + 1];
            int j = j0;
            for (; j + 16 <= j1; j += 16) {
                int idx[16];
#pragma unroll
                for (int q = 0; q < 16; ++q) idx[q] = csr_src[j + q];
                F2H u[16];
#pragma unroll
                for (int q = 0; q < 16; ++q)
                    u[q].f = reinterpret_cast<const float2*>(hin + (size_t)idx[q] * 64)[cg];
#pragma unroll
                for (int q = 0; q < 16; ++q) {
                    float2 g0 = __half22float2(u[q].h[0]);
                    float2 g1 = __half22float2(u[q].h[1]);
                    acc.x += g0.x; acc.y += g0.y; acc.z += g1.x; acc.w += g1.y;
                }
            }
            for (; j + 4 <= j1; j += 4) {
                int idx[4];
#pragma unroll
                for (int q = 0; q < 4; ++q) idx[q] = csr_src[j + q];
                F2H u[4];
#pragma unroll
                for (int q = 0; q < 4; ++q)
                    u[q].f = reinterpret_cast<const float2*>(hin + (size_t)idx[q] * 64)[cg];
#pragma unroll
                for (int q = 0; q < 4; ++q) {
                    float2 g0 = __half22float2(u[q].h[0]);
                    float2 g1 = __half22float2(u[q].h[1]);
                    acc.x += g0.x; acc.y += g0.y; acc.z += g1.x; acc.w += g1.y;
                }
            }
            for (; j < j1; ++j) {
                F2H u;
                u.f = reinterpret_cast<const float2*>(hin + (size_t)csr_src[j] * 64)[cg];
                float2 g0 = __half22float2(u.h[0]);
                float2 g1 = __half22float2(u.h[1]);
                acc.x += g0.x; acc.y += g0.y; acc.z += g1.x; acc.w += g1.y;
            }
        }
        F2H o;
        o.h[0] = __float22half2_rn(make_float2(acc.x, acc.y));
        o.h[1] = __float22half2_rn(make_float2(acc.z, acc.w));
        *reinterpret_cast<float2*>(&xs[rloc][cg * 4]) = o.f;
    }
    __syncthreads();

    // ---- Phase B: MFMA MLP; wave w owns rows [16w, 16w+16) of xs ----
    int wid = tid >> 6, l = tid & 63;
    int c = l & 15, g = l >> 4;
    int r_base = r0 + wid * 16;

    half4v a1[4];
#pragma unroll
    for (int kk = 0; kk < 4; ++kk)
        a1[kk] = *reinterpret_cast<const half4v*>(&xs[wid * 16 + c][g * 4 + kk * 16]);

    f32x4 acc1[4];
#pragma unroll
    for (int n = 0; n < 4; ++n) {
        const _Float16* bb = wt1 + (size_t)(n * 16 + c) * 64 + g * 4;
        half4v bf[4];
#pragma unroll
        for (int kk = 0; kk < 4; ++kk)
            bf[kk] = *reinterpret_cast<const half4v*>(bb + kk * 16);
        f32x4 z = {0.f, 0.f, 0.f, 0.f};
#pragma unroll
        for (int kk = 0; kk < 4; ++kk)
            z = __builtin_amdgcn_mfma_f32_16x16x16f16(a1[kk], bf[kk], z, 0, 0, 0);
        acc1[n] = z;
    }

    // bias + relu -> h1 transposed into own rows
#pragma unroll
    for (int n = 0; n < 4; ++n) {
        float bj = b1[n * 16 + c];
#pragma unroll
        for (int e = 0; e < 4; ++e) {
            float v = fmaxf(acc1[n][e] + bj, 0.f);
            xs[wid * 16 + g * 4 + e][n * 16 + c] = (_Float16)v;
        }
    }

    half4v a2[4];
#pragma unroll
    for (int kk = 0; kk < 4; ++kk)
        a2[kk] = *reinterpret_cast<const half4v*>(&xs[wid * 16 + c][kk * 16 + g * 4]);

    f32x4 acc2[4];
#pragma unroll
    for (int n = 0; n < 4; ++n) {
        const _Float16* bb = wt2 + (size_t)(n * 16 + c) * 64 + g * 4;
        half4v bf[4];
#pragma unroll
        for (int kk = 0; kk < 4; ++kk)
            bf[kk] = *reinterpret_cast<const half4v*>(bb + kk * 16);
        f32x4 z = {0.f, 0.f, 0.f, 0.f};
#pragma unroll
        for (int kk = 0; kk < 4; ++kk)
            z = __builtin_amdgcn_mfma_f32_16x16x16f16(a2[kk], bf[kk], z, 0, 0, 0);
        acc2[n] = z;
    }

    // bias + relu -> RAW h into own rows + masked BN stats
#pragma unroll
    for (int n = 0; n < 4; ++n) {
        float bj = b2[n * 16 + c];
        float s = 0.f, q = 0.f;
#pragma unroll
        for (int e = 0; e < 4; ++e) {
            float v = fmaxf(acc2[n][e] + bj, 0.f);
            xs[wid * 16 + g * 4 + e][n * 16 + c] = (_Float16)v;
            if (r_base + g * 4 + e < N_NODES) { s += v; q += v * v; }
        }
        atomicAdd(&sred[n * 16 + c], s);
        atomicAdd(&sred[64 + n * 16 + c], q);
    }

    // coalesced store: 2 passes of 8 rows, 8 lanes x 16 B per row
#pragma unroll
    for (int p = 0; p < 2; ++p) {
        int row = p * 8 + (l >> 3);
        int colh = (l & 7) * 8;
        int grow = r_base + row;
        if (grow < N_NODES) {
            float4 v = *reinterpret_cast<const float4*>(&xs[wid * 16 + row][colh]);
            *reinterpret_cast<float4*>(reinterpret_cast<__half*>(hout) +
                                       (size_t)grow * 64 + colh) = v;
        }
    }

    __syncthreads();
    if (tid < 128) atomicAdd(&stats[tid], sred[tid]);
}

// ---------------------------------------------------------------------------
// h' = relu(BN(h)) elementwise, fp16 -> fp16
__global__ __launch_bounds__(256) void bnrelu_k(const __half* hin,
                                                const float* __restrict__ stats,
                                                const float* __restrict__ g,
                                                const float* __restrict__ bt,
                                                __half* hout) {
    __shared__ float ssc[64], sof[64];
    int tid = threadIdx.x;
    if (tid < 64) {
        float mean = stats[tid] * (1.f / N_NODES);
        float var = stats[64 + tid] * (1.f / N_NODES) - mean * mean;
        float sc = g[tid] * rsqrtf(var + BN_EPS);
        ssc[tid] = sc;
        sof[tid] = bt[tid] - mean * sc;
    }
    __syncthreads();
    int gid = blockIdx.x * 256 + tid;      // one half8 (16 B) per thread
    if (gid >= N_NODES * 8) return;
    int c0 = (gid & 7) * 8;
    union { float4 f; __half2 h[4]; } u;
    u.f = reinterpret_cast<const float4*>(hin)[gid];
#pragma unroll
    for (int q = 0; q < 4; ++q) {
        float2 v = __half22float2(u.h[q]);
        v.x = fmaxf(fmaf(v.x, ssc[c0 + 2 * q], sof[c0 + 2 * q]), 0.f);
        v.y = fmaxf(fmaf(v.y, ssc[c0 + 2 * q + 1], sof[c0 + 2 * q + 1]), 0.f);
        u.h[q] = __float22half2_rn(v);
    }
    reinterpret_cast<float4*>(hout)[gid] = u.f;
}

// ---------------------------------------------------------------------------
// out[N x 16] = h' @ wl + bl   (h' fp16, already activated)
__global__ __launch_bounds__(256) void final_k(const __half* __restrict__ hin,
                                               const float* __restrict__ wl,
                                               const float* __restrict__ bl,
                                               float* __restrict__ out) {
    __shared__ float xs[64][68];
    __shared__ float wsh[64 * 16];
    __shared__ float bsh[16];
    int tid = threadIdx.x;
    int r0 = blockIdx.x * 64;

    reinterpret_cast<float4*>(wsh)[tid] = reinterpret_cast<const float4*>(wl)[tid];
    if (tid < 16) bsh[tid] = bl[tid];

    {
        int rr = tid >> 4, cg = tid & 15;
#pragma unroll
        for (int i = 0; i < 4; ++i) {
            int r = rr + i * 16;
            float4 v = make_float4(0.f, 0.f, 0.f, 0.f);
            if (r0 + r < N_NODES) {
                union { float2 f; __half2 h[2]; } u;
                u.f = reinterpret_cast<const float2*>(hin + (size_t)(r0 + r) * 64)[cg];
                float2 f0 = __half22float2(u.h[0]);
                float2 f1 = __half22float2(u.h[1]);
                v = make_float4(f0.x, f0.y, f1.x, f1.y);
            }
            xs[cg * 4 + 0][r] = v.x;
            xs[cg * 4 + 1][r] = v.y;
            xs[cg * 4 + 2][r] = v.z;
            xs[cg * 4 + 3][r] = v.w;
        }
    }
    __syncthreads();

    int tc = tid & 3, r = tid >> 2;
    int c = tc * 4;
    float acc0 = 0.f, acc1 = 0.f, acc2 = 0.f, acc3 = 0.f;
#pragma unroll 8
    for (int k = 0; k < 64; ++k) {
        float xv = xs[k][r];
        float4 wv = *reinterpret_cast<const float4*>(&wsh[k * 16 + c]);
        acc0 = fmaf(xv, wv.x, acc0);
        acc1 = fmaf(xv, wv.y, acc1);
        acc2 = fmaf(xv, wv.z, acc2);
        acc3 = fmaf(xv, wv.w, acc3);
    }
    int row = r0 + r;
    if (row < N_NODES) {
        float4 o = make_float4(acc0 + bsh[c], acc1 + bsh[c + 1], acc2 + bsh[c + 2], acc3 + bsh[c + 3]);
        *reinterpret_cast<float4*>(out + (size_t)row * 16 + c) = o;
    }
}

// ---------------------------------------------------------------------------
extern "C" void kernel_launch(void* const* d_in, const int* in_sizes, int n_in,
                              void* d_out, int out_size, void* d_ws, size_t ws_size,
                              hipStream_t stream) {
    const float* x = (const float*)d_in[0];
    const int* ei = (const int*)d_in[1];
    const int E = in_sizes[1] / 2;

    const float* eps[3] = {(const float*)d_in[2], (const float*)d_in[9], (const float*)d_in[16]};
    const float* w1[3]  = {(const float*)d_in[3], (const float*)d_in[10], (const float*)d_in[17]};
    const float* b1[3]  = {(const float*)d_in[4], (const float*)d_in[11], (const float*)d_in[18]};
    const float* w2[3]  = {(const float*)d_in[5], (const float*)d_in[12], (const float*)d_in[19]};
    const float* b2[3]  = {(const float*)d_in[6], (const float*)d_in[13], (const float*)d_in[20]};
    const float* g[3]   = {(const float*)d_in[7], (const float*)d_in[14], (const float*)d_in[21]};
    const float* bt[3]  = {(const float*)d_in[8], (const float*)d_in[15], (const float*)d_in[22]};
    const float* wl = (const float*)d_in[23];
    const float* bl = (const float*)d_in[24];

    // workspace layout (fp16 h buffers)
    __half* xh   = (__half*)d_ws;                           // N*64
    __half* ha   = xh + (size_t)N_NODES * 64;
    __half* hb   = ha + (size_t)N_NODES * 64;
    _Float16* wth = (_Float16*)(hb + (size_t)N_NODES * 64); // 6*4096
    float* stats = (float*)(wth + 6 * 4096);
    int* gcnt    = (int*)(stats + 384);
    int* cbase   = gcnt + NC;
    int* gcursor = cbase + (NC + 1);
    int* row_ptr = gcursor + NC;
    int* tail    = row_ptr + (N_NODES + 1);
    size_t used  = (size_t)((char*)tail - (char*)d_ws);

    int* csr_src = tail;                 // E ints, persists through all layers
    int* part;                           // E ints, build-only
    if (used + 2 * (size_t)E * 4 <= ws_size) {
        part = csr_src + E;
    } else {
        part = (int*)d_out;  // consumed by csrD_k before final_k writes d_out
    }

    const int n4 = N_NODES * 16;

    // ---- one-time: CSR build (coarse partition + per-bucket sort) + converts ----
    zero_misc_k<<<2, 256, 0, stream>>>(stats, gcnt);
    tofp16_k<<<(n4 + 255) / 256, 256, 0, stream>>>(x, xh, n4);
    wtr_k<<<6, 256, 0, stream>>>(w1[0], w2[0], w1[1], w2[1], w1[2], w2[2], wth);
    histC_k<<<PART_BLOCKS, 256, 0, stream>>>(ei, gcnt, E);
    scanC_k<<<1, 256, 0, stream>>>(gcnt, cbase, gcursor);
    partC_k<<<PART_BLOCKS, 256, 0, stream>>>(ei, gcursor, part, E);
    csrD_k<<<NC, 256, 0, stream>>>(part, cbase, row_ptr, csr_src);

    const int bnblk = (N_NODES * 8 + 255) / 256; // 3125

    // ---- 3 fused GIN layers ----
    layer_k<<<NBLK64, 256, 0, stream>>>(xh, row_ptr, csr_src, eps[0],
                                        wth + 0 * 4096, b1[0], wth + 1 * 4096, b2[0],
                                        ha, stats + 0);
    bnrelu_k<<<bnblk, 256, 0, stream>>>(ha, stats + 0, g[0], bt[0], ha);

    layer_k<<<NBLK64, 256, 0, stream>>>(ha, row_ptr, csr_src, eps[1],
                                        wth + 2 * 4096, b1[1], wth + 3 * 4096, b2[1],
                                        hb, stats + 128);
    bnrelu_k<<<bnblk, 256, 0, stream>>>(hb, stats + 128, g[1], bt[1], hb);

    layer_k<<<NBLK64, 256, 0, stream>>>(hb, row_ptr, csr_src, eps[2],
                                        wth + 4 * 4096, b1[2], wth + 5 * 4096, b2[2],
                                        ha, stats + 256);
    bnrelu_k<<<bnblk, 256, 0, stream>>>(ha, stats + 256, g[2], bt[2], ha);

    // ---- final linear ----
    final_k<<<(N_NODES + 63) / 64, 256, 0, stream>>>(ha, wl, bl, (float*)d_out);
}

// Round 16
// 343.736 us; speedup vs baseline: 1.1310x; 1.1310x over previous
//
#include <hip/hip_runtime.h>
#include <hip/hip_fp16.h>
#include <math.h>

#define N_NODES 100000
#define NC 391               // ceil(N_NODES/256) coarse buckets (256 nodes each)
#define NBLK64 1563          // ceil(N_NODES/64)
#define BN_EPS 1e-5f
#define PART_BLOCKS 128

typedef _Float16 half4v __attribute__((ext_vector_type(4)));
typedef float f32x4 __attribute__((ext_vector_type(4)));

// ---------------------------------------------------------------------------
__global__ void zero_misc_k(float* stats, int* gcnt) {
    int gid = blockIdx.x * blockDim.x + threadIdx.x;
    if (gid < 384) stats[gid] = 0.f;
    if (gid < NC) gcnt[gid] = 0;
}

// x fp32 -> fp16 (4 elems per thread)
__global__ void tofp16_k(const float* __restrict__ x, __half* __restrict__ xh, int n4) {
    int gid = blockIdx.x * blockDim.x + threadIdx.x;
    if (gid >= n4) return;
    float4 v = reinterpret_cast<const float4*>(x)[gid];
    union { float2 f; __half2 h[2]; } u;
    u.h[0] = __float22half2_rn(make_float2(v.x, v.y));
    u.h[1] = __float22half2_rn(make_float2(v.z, v.w));
    reinterpret_cast<float2*>(xh)[gid] = u.f;
}

// transpose + fp16-convert the six 64x64 MLP weights: Wt[c][k] = fp16(W[k][c])
__global__ void wtr_k(const float* w0, const float* w1, const float* w2,
                      const float* w3, const float* w4, const float* w5,
                      _Float16* wth) {
    const float* src[6] = {w0, w1, w2, w3, w4, w5};
    const float* W = src[blockIdx.x];
    _Float16* D = wth + (size_t)blockIdx.x * 4096;
    for (int idx = threadIdx.x; idx < 4096; idx += 256) {
        int k = idx >> 6, c = idx & 63;
        D[c * 64 + k] = (_Float16)W[idx];
    }
}

// coarse histogram: bucket = dst >> 8
__global__ __launch_bounds__(256) void histC_k(const int* __restrict__ ei,
                                               int* __restrict__ gcnt, int E) {
    __shared__ int cnt[NC];
    for (int i = threadIdx.x; i < NC; i += 256) cnt[i] = 0;
    __syncthreads();
    int per = (E + gridDim.x - 1) / gridDim.x;
    int s0 = blockIdx.x * per, s1 = min(E, s0 + per);
    for (int e = s0 + threadIdx.x; e < s1; e += 256)
        atomicAdd(&cnt[ei[E + e] >> 8], 1);
    __syncthreads();
    for (int i = threadIdx.x; i < NC; i += 256)
        if (cnt[i]) atomicAdd(&gcnt[i], cnt[i]);
}

// exclusive scan of NC coarse counts (single block, 2 elems/thread)
__global__ __launch_bounds__(256) void scanC_k(const int* __restrict__ gcnt,
                                               int* __restrict__ cbase,
                                               int* __restrict__ gcursor) {
    __shared__ int tmp[256];
    int t = threadIdx.x;
    int v0 = (2 * t < NC) ? gcnt[2 * t] : 0;
    int v1 = (2 * t + 1 < NC) ? gcnt[2 * t + 1] : 0;
    int s = v0 + v1;
    tmp[t] = s;
    __syncthreads();
    for (int off = 1; off < 256; off <<= 1) {
        int a = (t >= off) ? tmp[t - off] : 0;
        __syncthreads();
        tmp[t] += a;
        __syncthreads();
    }
    int run = tmp[t] - s;
    if (2 * t < NC) { cbase[2 * t] = run; gcursor[2 * t] = run; }
    run += v0;
    if (2 * t + 1 < NC) { cbase[2 * t + 1] = run; gcursor[2 * t + 1] = run; }
    if (t == 255) cbase[NC] = tmp[255];  // == E
}

// coarse partition: part[] entries = (dst&255)<<17 | src, coarse-contiguous.
__global__ __launch_bounds__(256) void partC_k(const int* __restrict__ ei,
                                               int* __restrict__ gcursor,
                                               int* __restrict__ part, int E) {
    __shared__ int cnt[NC];
    __shared__ int base[NC];
    for (int i = threadIdx.x; i < NC; i += 256) cnt[i] = 0;
    __syncthreads();
    int per = (E + gridDim.x - 1) / gridDim.x;
    int s0 = blockIdx.x * per, s1 = min(E, s0 + per);
    for (int e = s0 + threadIdx.x; e < s1; e += 256)
        atomicAdd(&cnt[ei[E + e] >> 8], 1);
    __syncthreads();
    for (int i = threadIdx.x; i < NC; i += 256) {
        int c = cnt[i];
        base[i] = c ? atomicAdd(&gcursor[i], c) : 0;
    }
    __syncthreads();
    for (int i = threadIdx.x; i < NC; i += 256) cnt[i] = 0;
    __syncthreads();
    for (int e = s0 + threadIdx.x; e < s1; e += 256) {
        int s = ei[e], d = ei[E + e];
        int b = d >> 8, dl = d & 255;
        int lo = atomicAdd(&cnt[b], 1);
        part[base[b] + lo] = (dl << 17) | s;
    }
}

// per-coarse-bucket counting sort -> row_ptr + node-ordered csr_src.
__global__ __launch_bounds__(256) void csrD_k(const int* __restrict__ part,
                                              const int* __restrict__ cbase,
                                              int* __restrict__ row_ptr,
                                              int* __restrict__ csr_src) {
    __shared__ int cnt[256];
    __shared__ int tmp[256];
    __shared__ int cur[256];
    int b = blockIdx.x;
    int t = threadIdx.x;
    int e0 = cbase[b], e1 = cbase[b + 1];
    cnt[t] = 0;
    __syncthreads();
    for (int i = e0 + t; i < e1; i += 256) atomicAdd(&cnt[(part[i] >> 17) & 255], 1);
    __syncthreads();
    int c = cnt[t];
    tmp[t] = c;
    __syncthreads();
    for (int off = 1; off < 256; off <<= 1) {
        int a = (t >= off) ? tmp[t - off] : 0;
        __syncthreads();
        tmp[t] += a;
        __syncthreads();
    }
    int excl = tmp[t] - c;
    int node = b * 256 + t;
    if (node < N_NODES) row_ptr[node] = e0 + excl;
    cur[t] = e0 + excl;
    __syncthreads();
    for (int i = e0 + t; i < e1; i += 256) {
        int u = part[i];
        int dl = (u >> 17) & 255;
        int pos = atomicAdd(&cur[dl], 1);
        csr_src[pos] = u & 0x1FFFF;
    }
    if (b == NC - 1 && t == 0) row_ptr[N_NODES] = cbase[NC];
}

// ---------------------------------------------------------------------------
// Fused GIN layer: block = 64 nodes, 256 threads, ~9.7 KB LDS.
// Phase A: register gather at float4 (16 B) per lane: 8 lanes cover a 128 B
//          row -> one wave instruction touches 8 lines (2x line-parallelism
//          vs 8 B/lane), 8-deep pipeline, fp32 accumulation -> xs.
// Phase B: MFMA MLP (v_mfma_f32_16x16x16_f16), h1 per-wave in xs; store + stats.
__global__ __launch_bounds__(256) void layer_k(
    const __half* __restrict__ hin,
    const int* __restrict__ row_ptr, const int* __restrict__ csr_src,
    const float* __restrict__ epsp,
    const _Float16* __restrict__ wt1, const float* __restrict__ b1,
    const _Float16* __restrict__ wt2, const float* __restrict__ b2,
    __half* __restrict__ hout, float* __restrict__ stats) {
    __shared__ _Float16 xs[64][72];     // row-major gathered tile / h1 / h buffer
    __shared__ float sred[128];

    int tid = threadIdx.x;
    int r0 = blockIdx.x * 64;
    if (tid < 128) sred[tid] = 0.f;

    float eps1 = 1.0f + *epsp;
    int cg8 = tid & 7;    // which 16 B slice of the row (8 halfs)
    int lg8 = tid >> 3;   // 0..31: lane-group id
    union F4H { float4 f; __half2 h[4]; };

    // ---- Phase A: gather, 8 lanes/node, 2 node-passes, 8-deep pipeline ----
#pragma unroll
    for (int i = 0; i < 2; ++i) {
        int rloc = lg8 + i * 32;
        int node = r0 + rloc;
        float acc[8] = {0.f, 0.f, 0.f, 0.f, 0.f, 0.f, 0.f, 0.f};
        if (node < N_NODES) {
            F4H sv;
            sv.f = reinterpret_cast<const float4*>(hin + (size_t)node * 64)[cg8];
#pragma unroll
            for (int p = 0; p < 4; ++p) {
                float2 gg = __half22float2(sv.h[p]);
                acc[2 * p] = gg.x * eps1;
                acc[2 * p + 1] = gg.y * eps1;
            }
            int j0 = row_ptr[node], j1 = row_ptr[node + 1];
            int j = j0;
            for (; j + 8 <= j1; j += 8) {
                int idx[8];
#pragma unroll
                for (int q = 0; q < 8; ++q) idx[q] = csr_src[j + q];
                F4H u[8];
#pragma unroll
                for (int q = 0; q < 8; ++q)
                    u[q].f = reinterpret_cast<const float4*>(hin + (size_t)idx[q] * 64)[cg8];
#pragma unroll
                for (int q = 0; q < 8; ++q) {
#pragma unroll
                    for (int p = 0; p < 4; ++p) {
                        float2 gg = __half22float2(u[q].h[p]);
                        acc[2 * p] += gg.x;
                        acc[2 * p + 1] += gg.y;
                    }
                }
            }
            for (; j + 2 <= j1; j += 2) {
                int ia = csr_src[j], ib = csr_src[j + 1];
                F4H ua, ub;
                ua.f = reinterpret_cast<const float4*>(hin + (size_t)ia * 64)[cg8];
                ub.f = reinterpret_cast<const float4*>(hin + (size_t)ib * 64)[cg8];
#pragma unroll
                for (int p = 0; p < 4; ++p) {
                    float2 ga = __half22float2(ua.h[p]);
                    float2 gb = __half22float2(ub.h[p]);
                    acc[2 * p] += ga.x + gb.x;
                    acc[2 * p + 1] += ga.y + gb.y;
                }
            }
            for (; j < j1; ++j) {
                F4H u;
                u.f = reinterpret_cast<const float4*>(hin + (size_t)csr_src[j] * 64)[cg8];
#pragma unroll
                for (int p = 0; p < 4; ++p) {
                    float2 gg = __half22float2(u.h[p]);
                    acc[2 * p] += gg.x;
                    acc[2 * p + 1] += gg.y;
                }
            }
        }
        F4H o;
#pragma unroll
        for (int p = 0; p < 4; ++p)
            o.h[p] = __float22half2_rn(make_float2(acc[2 * p], acc[2 * p + 1]));
        *reinterpret_cast<float4*>(&xs[rloc][cg8 * 8]) = o.f;
    }
    __syncthreads();

    // ---- Phase B: MFMA MLP; wave w owns rows [16w, 16w+16) of xs ----
    int wid = tid >> 6, l = tid & 63;
    int c = l & 15, g = l >> 4;
    int r_base = r0 + wid * 16;

    half4v a1[4];
#pragma unroll
    for (int kk = 0; kk < 4; ++kk)
        a1[kk] = *reinterpret_cast<const half4v*>(&xs[wid * 16 + c][g * 4 + kk * 16]);

    f32x4 acc1[4];
#pragma unroll
    for (int n = 0; n < 4; ++n) {
        const _Float16* bb = wt1 + (size_t)(n * 16 + c) * 64 + g * 4;
        half4v bf[4];
#pragma unroll
        for (int kk = 0; kk < 4; ++kk)
            bf[kk] = *reinterpret_cast<const half4v*>(bb + kk * 16);
        f32x4 z = {0.f, 0.f, 0.f, 0.f};
#pragma unroll
        for (int kk = 0; kk < 4; ++kk)
            z = __builtin_amdgcn_mfma_f32_16x16x16f16(a1[kk], bf[kk], z, 0, 0, 0);
        acc1[n] = z;
    }

    // bias + relu -> h1 transposed into own rows
#pragma unroll
    for (int n = 0; n < 4; ++n) {
        float bj = b1[n * 16 + c];
#pragma unroll
        for (int e = 0; e < 4; ++e) {
            float v = fmaxf(acc1[n][e] + bj, 0.f);
            xs[wid * 16 + g * 4 + e][n * 16 + c] = (_Float16)v;
        }
    }

    half4v a2[4];
#pragma unroll
    for (int kk = 0; kk < 4; ++kk)
        a2[kk] = *reinterpret_cast<const half4v*>(&xs[wid * 16 + c][kk * 16 + g * 4]);

    f32x4 acc2[4];
#pragma unroll
    for (int n = 0; n < 4; ++n) {
        const _Float16* bb = wt2 + (size_t)(n * 16 + c) * 64 + g * 4;
        half4v bf[4];
#pragma unroll
        for (int kk = 0; kk < 4; ++kk)
            bf[kk] = *reinterpret_cast<const half4v*>(bb + kk * 16);
        f32x4 z = {0.f, 0.f, 0.f, 0.f};
#pragma unroll
        for (int kk = 0; kk < 4; ++kk)
            z = __builtin_amdgcn_mfma_f32_16x16x16f16(a2[kk], bf[kk], z, 0, 0, 0);
        acc2[n] = z;
    }

    // bias + relu -> RAW h into own rows + masked BN stats
#pragma unroll
    for (int n = 0; n < 4; ++n) {
        float bj = b2[n * 16 + c];
        float s = 0.f, q = 0.f;
#pragma unroll
        for (int e = 0; e < 4; ++e) {
            float v = fmaxf(acc2[n][e] + bj, 0.f);
            xs[wid * 16 + g * 4 + e][n * 16 + c] = (_Float16)v;
            if (r_base + g * 4 + e < N_NODES) { s += v; q += v * v; }
        }
        atomicAdd(&sred[n * 16 + c], s);
        atomicAdd(&sred[64 + n * 16 + c], q);
    }

    // coalesced store: 2 passes of 8 rows, 8 lanes x 16 B per row
#pragma unroll
    for (int p = 0; p < 2; ++p) {
        int row = p * 8 + (l >> 3);
        int colh = (l & 7) * 8;
        int grow = r_base + row;
        if (grow < N_NODES) {
            float4 v = *reinterpret_cast<const float4*>(&xs[wid * 16 + row][colh]);
            *reinterpret_cast<float4*>(reinterpret_cast<__half*>(hout) +
                                       (size_t)grow * 64 + colh) = v;
        }
    }

    __syncthreads();
    if (tid < 128) atomicAdd(&stats[tid], sred[tid]);
}

// ---------------------------------------------------------------------------
// h' = relu(BN(h)) elementwise, fp16 -> fp16
__global__ __launch_bounds__(256) void bnrelu_k(const __half* hin,
                                                const float* __restrict__ stats,
                                                const float* __restrict__ g,
                                                const float* __restrict__ bt,
                                                __half* hout) {
    __shared__ float ssc[64], sof[64];
    int tid = threadIdx.x;
    if (tid < 64) {
        float mean = stats[tid] * (1.f / N_NODES);
        float var = stats[64 + tid] * (1.f / N_NODES) - mean * mean;
        float sc = g[tid] * rsqrtf(var + BN_EPS);
        ssc[tid] = sc;
        sof[tid] = bt[tid] - mean * sc;
    }
    __syncthreads();
    int gid = blockIdx.x * 256 + tid;      // one half8 (16 B) per thread
    if (gid >= N_NODES * 8) return;
    int c0 = (gid & 7) * 8;
    union { float4 f; __half2 h[4]; } u;
    u.f = reinterpret_cast<const float4*>(hin)[gid];
#pragma unroll
    for (int q = 0; q < 4; ++q) {
        float2 v = __half22float2(u.h[q]);
        v.x = fmaxf(fmaf(v.x, ssc[c0 + 2 * q], sof[c0 + 2 * q]), 0.f);
        v.y = fmaxf(fmaf(v.y, ssc[c0 + 2 * q + 1], sof[c0 + 2 * q + 1]), 0.f);
        u.h[q] = __float22half2_rn(v);
    }
    reinterpret_cast<float4*>(hout)[gid] = u.f;
}

// ---------------------------------------------------------------------------
// out[N x 16] = h' @ wl + bl   (h' fp16, already activated)
__global__ __launch_bounds__(256) void final_k(const __half* __restrict__ hin,
                                               const float* __restrict__ wl,
                                               const float* __restrict__ bl,
                                               float* __restrict__ out) {
    __shared__ float xs[64][68];
    __shared__ float wsh[64 * 16];
    __shared__ float bsh[16];
    int tid = threadIdx.x;
    int r0 = blockIdx.x * 64;

    reinterpret_cast<float4*>(wsh)[tid] = reinterpret_cast<const float4*>(wl)[tid];
    if (tid < 16) bsh[tid] = bl[tid];

    {
        int rr = tid >> 4, cg = tid & 15;
#pragma unroll
        for (int i = 0; i < 4; ++i) {
            int r = rr + i * 16;
            float4 v = make_float4(0.f, 0.f, 0.f, 0.f);
            if (r0 + r < N_NODES) {
                union { float2 f; __half2 h[2]; } u;
                u.f = reinterpret_cast<const float2*>(hin + (size_t)(r0 + r) * 64)[cg];
                float2 f0 = __half22float2(u.h[0]);
                float2 f1 = __half22float2(u.h[1]);
                v = make_float4(f0.x, f0.y, f1.x, f1.y);
            }
            xs[cg * 4 + 0][r] = v.x;
            xs[cg * 4 + 1][r] = v.y;
            xs[cg * 4 + 2][r] = v.z;
            xs[cg * 4 + 3][r] = v.w;
        }
    }
    __syncthreads();

    int tc = tid & 3, r = tid >> 2;
    int c = tc * 4;
    float acc0 = 0.f, acc1 = 0.f, acc2 = 0.f, acc3 = 0.f;
#pragma unroll 8
    for (int k = 0; k < 64; ++k) {
        float xv = xs[k][r];
        float4 wv = *reinterpret_cast<const float4*>(&wsh[k * 16 + c]);
        acc0 = fmaf(xv, wv.x, acc0);
        acc1 = fmaf(xv, wv.y, acc1);
        acc2 = fmaf(xv, wv.z, acc2);
        acc3 = fmaf(xv, wv.w, acc3);
    }
    int row = r0 + r;
    if (row < N_NODES) {
        float4 o = make_float4(acc0 + bsh[c], acc1 + bsh[c + 1], acc2 + bsh[c + 2], acc3 + bsh[c + 3]);
        *reinterpret_cast<float4*>(out + (size_t)row * 16 + c) = o;
    }
}

// ---------------------------------------------------------------------------
extern "C" void kernel_launch(void* const* d_in, const int* in_sizes, int n_in,
                              void* d_out, int out_size, void* d_ws, size_t ws_size,
                              hipStream_t stream) {
    const float* x = (const float*)d_in[0];
    const int* ei = (const int*)d_in[1];
    const int E = in_sizes[1] / 2;

    const float* eps[3] = {(const float*)d_in[2], (const float*)d_in[9], (const float*)d_in[16]};
    const float* w1[3]  = {(const float*)d_in[3], (const float*)d_in[10], (const float*)d_in[17]};
    const float* b1[3]  = {(const float*)d_in[4], (const float*)d_in[11], (const float*)d_in[18]};
    const float* w2[3]  = {(const float*)d_in[5], (const float*)d_in[12], (const float*)d_in[19]};
    const float* b2[3]  = {(const float*)d_in[6], (const float*)d_in[13], (const float*)d_in[20]};
    const float* g[3]   = {(const float*)d_in[7], (const float*)d_in[14], (const float*)d_in[21]};
    const float* bt[3]  = {(const float*)d_in[8], (const float*)d_in[15], (const float*)d_in[22]};
    const float* wl = (const float*)d_in[23];
    const float* bl = (const float*)d_in[24];

    // workspace layout (fp16 h buffers)
    __half* xh   = (__half*)d_ws;                           // N*64
    __half* ha   = xh + (size_t)N_NODES * 64;
    __half* hb   = ha + (size_t)N_NODES * 64;
    _Float16* wth = (_Float16*)(hb + (size_t)N_NODES * 64); // 6*4096
    float* stats = (float*)(wth + 6 * 4096);
    int* gcnt    = (int*)(stats + 384);
    int* cbase   = gcnt + NC;
    int* gcursor = cbase + (NC + 1);
    int* row_ptr = gcursor + NC;
    int* tail    = row_ptr + (N_NODES + 1);
    size_t used  = (size_t)((char*)tail - (char*)d_ws);

    int* csr_src = tail;                 // E ints, persists through all layers
    int* part;                           // E ints, build-only
    if (used + 2 * (size_t)E * 4 <= ws_size) {
        part = csr_src + E;
    } else {
        part = (int*)d_out;  // consumed by csrD_k before final_k writes d_out
    }

    const int n4 = N_NODES * 16;

    // ---- one-time: CSR build (coarse partition + per-bucket sort) + converts ----
    zero_misc_k<<<2, 256, 0, stream>>>(stats, gcnt);
    tofp16_k<<<(n4 + 255) / 256, 256, 0, stream>>>(x, xh, n4);
    wtr_k<<<6, 256, 0, stream>>>(w1[0], w2[0], w1[1], w2[1], w1[2], w2[2], wth);
    histC_k<<<PART_BLOCKS, 256, 0, stream>>>(ei, gcnt, E);
    scanC_k<<<1, 256, 0, stream>>>(gcnt, cbase, gcursor);
    partC_k<<<PART_BLOCKS, 256, 0, stream>>>(ei, gcursor, part, E);
    csrD_k<<<NC, 256, 0, stream>>>(part, cbase, row_ptr, csr_src);

    const int bnblk = (N_NODES * 8 + 255) / 256; // 3125

    // ---- 3 fused GIN layers ----
    layer_k<<<NBLK64, 256, 0, stream>>>(xh, row_ptr, csr_src, eps[0],
                                        wth + 0 * 4096, b1[0], wth + 1 * 4096, b2[0],
                                        ha, stats + 0);
    bnrelu_k<<<bnblk, 256, 0, stream>>>(ha, stats + 0, g[0], bt[0], ha);

    layer_k<<<NBLK64, 256, 0, stream>>>(ha, row_ptr, csr_src, eps[1],
                                        wth + 2 * 4096, b1[1], wth + 3 * 4096, b2[1],
                                        hb, stats + 128);
    bnrelu_k<<<bnblk, 256, 0, stream>>>(hb, stats + 128, g[1], bt[1], hb);

    layer_k<<<NBLK64, 256, 0, stream>>>(hb, row_ptr, csr_src, eps[2],
                                        wth + 4 * 4096, b1[2], wth + 5 * 4096, b2[2],
                                        ha, stats + 256);
    bnrelu_k<<<bnblk, 256, 0, stream>>>(ha, stats + 256, g[2], bt[2], ha);

    // ---- final linear ----
    final_k<<<(N_NODES + 63) / 64, 256, 0, stream>>>(ha, wl, bl, (float*)d_out);
}

// Round 17
// 334.647 us; speedup vs baseline: 1.1617x; 1.0272x over previous
//
#include <hip/hip_runtime.h>
#include <hip/hip_fp16.h>
#include <math.h>

#define N_NODES 100000
#define NC 391               // ceil(N_NODES/256) coarse buckets (256 nodes each)
#define NBLK64 1563          // ceil(N_NODES/64)
#define BN_EPS 1e-5f
#define PART_BLOCKS 128

typedef _Float16 half4v __attribute__((ext_vector_type(4)));
typedef float f32x4 __attribute__((ext_vector_type(4)));

// ---------------------------------------------------------------------------
__global__ void zero_misc_k(float* stats, int* gcnt) {
    int gid = blockIdx.x * blockDim.x + threadIdx.x;
    if (gid < 384) stats[gid] = 0.f;
    if (gid < NC) gcnt[gid] = 0;
}

// x fp32 -> fp16 (4 elems per thread)
__global__ void tofp16_k(const float* __restrict__ x, __half* __restrict__ xh, int n4) {
    int gid = blockIdx.x * blockDim.x + threadIdx.x;
    if (gid >= n4) return;
    float4 v = reinterpret_cast<const float4*>(x)[gid];
    union { float2 f; __half2 h[2]; } u;
    u.h[0] = __float22half2_rn(make_float2(v.x, v.y));
    u.h[1] = __float22half2_rn(make_float2(v.z, v.w));
    reinterpret_cast<float2*>(xh)[gid] = u.f;
}

// transpose + fp16-convert the six 64x64 MLP weights: Wt[c][k] = fp16(W[k][c])
__global__ void wtr_k(const float* w0, const float* w1, const float* w2,
                      const float* w3, const float* w4, const float* w5,
                      _Float16* wth) {
    const float* src[6] = {w0, w1, w2, w3, w4, w5};
    const float* W = src[blockIdx.x];
    _Float16* D = wth + (size_t)blockIdx.x * 4096;
    for (int idx = threadIdx.x; idx < 4096; idx += 256) {
        int k = idx >> 6, c = idx & 63;
        D[c * 64 + k] = (_Float16)W[idx];
    }
}

// coarse histogram: bucket = dst >> 8
__global__ __launch_bounds__(256) void histC_k(const int* __restrict__ ei,
                                               int* __restrict__ gcnt, int E) {
    __shared__ int cnt[NC];
    for (int i = threadIdx.x; i < NC; i += 256) cnt[i] = 0;
    __syncthreads();
    int per = (E + gridDim.x - 1) / gridDim.x;
    int s0 = blockIdx.x * per, s1 = min(E, s0 + per);
    for (int e = s0 + threadIdx.x; e < s1; e += 256)
        atomicAdd(&cnt[ei[E + e] >> 8], 1);
    __syncthreads();
    for (int i = threadIdx.x; i < NC; i += 256)
        if (cnt[i]) atomicAdd(&gcnt[i], cnt[i]);
}

// exclusive scan of NC coarse counts (single block, 2 elems/thread)
__global__ __launch_bounds__(256) void scanC_k(const int* __restrict__ gcnt,
                                               int* __restrict__ cbase,
                                               int* __restrict__ gcursor) {
    __shared__ int tmp[256];
    int t = threadIdx.x;
    int v0 = (2 * t < NC) ? gcnt[2 * t] : 0;
    int v1 = (2 * t + 1 < NC) ? gcnt[2 * t + 1] : 0;
    int s = v0 + v1;
    tmp[t] = s;
    __syncthreads();
    for (int off = 1; off < 256; off <<= 1) {
        int a = (t >= off) ? tmp[t - off] : 0;
        __syncthreads();
        tmp[t] += a;
        __syncthreads();
    }
    int run = tmp[t] - s;
    if (2 * t < NC) { cbase[2 * t] = run; gcursor[2 * t] = run; }
    run += v0;
    if (2 * t + 1 < NC) { cbase[2 * t + 1] = run; gcursor[2 * t + 1] = run; }
    if (t == 255) cbase[NC] = tmp[255];  // == E
}

// coarse partition: part[] entries = (dst&255)<<17 | src, coarse-contiguous.
__global__ __launch_bounds__(256) void partC_k(const int* __restrict__ ei,
                                               int* __restrict__ gcursor,
                                               int* __restrict__ part, int E) {
    __shared__ int cnt[NC];
    __shared__ int base[NC];
    for (int i = threadIdx.x; i < NC; i += 256) cnt[i] = 0;
    __syncthreads();
    int per = (E + gridDim.x - 1) / gridDim.x;
    int s0 = blockIdx.x * per, s1 = min(E, s0 + per);
    for (int e = s0 + threadIdx.x; e < s1; e += 256)
        atomicAdd(&cnt[ei[E + e] >> 8], 1);
    __syncthreads();
    for (int i = threadIdx.x; i < NC; i += 256) {
        int c = cnt[i];
        base[i] = c ? atomicAdd(&gcursor[i], c) : 0;
    }
    __syncthreads();
    for (int i = threadIdx.x; i < NC; i += 256) cnt[i] = 0;
    __syncthreads();
    for (int e = s0 + threadIdx.x; e < s1; e += 256) {
        int s = ei[e], d = ei[E + e];
        int b = d >> 8, dl = d & 255;
        int lo = atomicAdd(&cnt[b], 1);
        part[base[b] + lo] = (dl << 17) | s;
    }
}

// per-coarse-bucket counting sort -> row_ptr + node-ordered csr_src.
__global__ __launch_bounds__(256) void csrD_k(const int* __restrict__ part,
                                              const int* __restrict__ cbase,
                                              int* __restrict__ row_ptr,
                                              int* __restrict__ csr_src) {
    __shared__ int cnt[256];
    __shared__ int tmp[256];
    __shared__ int cur[256];
    int b = blockIdx.x;
    int t = threadIdx.x;
    int e0 = cbase[b], e1 = cbase[b + 1];
    cnt[t] = 0;
    __syncthreads();
    for (int i = e0 + t; i < e1; i += 256) atomicAdd(&cnt[(part[i] >> 17) & 255], 1);
    __syncthreads();
    int c = cnt[t];
    tmp[t] = c;
    __syncthreads();
    for (int off = 1; off < 256; off <<= 1) {
        int a = (t >= off) ? tmp[t - off] : 0;
        __syncthreads();
        tmp[t] += a;
        __syncthreads();
    }
    int excl = tmp[t] - c;
    int node = b * 256 + t;
    if (node < N_NODES) row_ptr[node] = e0 + excl;
    cur[t] = e0 + excl;
    __syncthreads();
    for (int i = e0 + t; i < e1; i += 256) {
        int u = part[i];
        int dl = (u >> 17) & 255;
        int pos = atomicAdd(&cur[dl], 1);
        csr_src[pos] = u & 0x1FFFF;
    }
    if (b == NC - 1 && t == 0) row_ptr[N_NODES] = cbase[NC];
}

// ---------------------------------------------------------------------------
// Fused GIN layer: block = 64 nodes, 512 threads (8 waves), ~9.7 KB LDS.
// Phase A: gather, 8 lanes/node x 64 nodes (one pass per lane), float4 loads,
//          8-deep pipeline.
// Phase B: MFMA MLP split across wave pairs: strip=wid&3 owns rows
//          [16*strip,16*strip+16), half=wid>>2 owns 2 of the 4 N-tiles.
__global__ __launch_bounds__(512) void layer_k(
    const __half* __restrict__ hin,
    const int* __restrict__ row_ptr, const int* __restrict__ csr_src,
    const float* __restrict__ epsp,
    const _Float16* __restrict__ wt1, const float* __restrict__ b1,
    const _Float16* __restrict__ wt2, const float* __restrict__ b2,
    __half* __restrict__ hout, float* __restrict__ stats) {
    __shared__ _Float16 xs[64][72];     // gathered tile / h1 / h buffer
    __shared__ float sred[128];

    int tid = threadIdx.x;
    int r0 = blockIdx.x * 64;
    if (tid < 128) sred[tid] = 0.f;

    float eps1 = 1.0f + *epsp;
    int cg8 = tid & 7;    // 16 B slice of the row
    int rloc = tid >> 3;  // 0..63: node within tile
    union F4H { float4 f; __half2 h[4]; };

    // ---- Phase A: gather (one node per lane-group) ----
    {
        int node = r0 + rloc;
        float acc[8] = {0.f, 0.f, 0.f, 0.f, 0.f, 0.f, 0.f, 0.f};
        if (node < N_NODES) {
            F4H sv;
            sv.f = reinterpret_cast<const float4*>(hin + (size_t)node * 64)[cg8];
#pragma unroll
            for (int p = 0; p < 4; ++p) {
                float2 gg = __half22float2(sv.h[p]);
                acc[2 * p] = gg.x * eps1;
                acc[2 * p + 1] = gg.y * eps1;
            }
            int j0 = row_ptr[node], j1 = row_ptr[node + 1];
            int j = j0;
            for (; j + 8 <= j1; j += 8) {
                int idx[8];
#pragma unroll
                for (int q = 0; q < 8; ++q) idx[q] = csr_src[j + q];
                F4H u[8];
#pragma unroll
                for (int q = 0; q < 8; ++q)
                    u[q].f = reinterpret_cast<const float4*>(hin + (size_t)idx[q] * 64)[cg8];
#pragma unroll
                for (int q = 0; q < 8; ++q) {
#pragma unroll
                    for (int p = 0; p < 4; ++p) {
                        float2 gg = __half22float2(u[q].h[p]);
                        acc[2 * p] += gg.x;
                        acc[2 * p + 1] += gg.y;
                    }
                }
            }
            for (; j + 2 <= j1; j += 2) {
                int ia = csr_src[j], ib = csr_src[j + 1];
                F4H ua, ub;
                ua.f = reinterpret_cast<const float4*>(hin + (size_t)ia * 64)[cg8];
                ub.f = reinterpret_cast<const float4*>(hin + (size_t)ib * 64)[cg8];
#pragma unroll
                for (int p = 0; p < 4; ++p) {
                    float2 ga = __half22float2(ua.h[p]);
                    float2 gb = __half22float2(ub.h[p]);
                    acc[2 * p] += ga.x + gb.x;
                    acc[2 * p + 1] += ga.y + gb.y;
                }
            }
            for (; j < j1; ++j) {
                F4H u;
                u.f = reinterpret_cast<const float4*>(hin + (size_t)csr_src[j] * 64)[cg8];
#pragma unroll
                for (int p = 0; p < 4; ++p) {
                    float2 gg = __half22float2(u.h[p]);
                    acc[2 * p] += gg.x;
                    acc[2 * p + 1] += gg.y;
                }
            }
        }
        F4H o;
#pragma unroll
        for (int p = 0; p < 4; ++p)
            o.h[p] = __float22half2_rn(make_float2(acc[2 * p], acc[2 * p + 1]));
        *reinterpret_cast<float4*>(&xs[rloc][cg8 * 8]) = o.f;
    }
    __syncthreads();

    // ---- Phase B: MFMA MLP; wave pair (strip, half) ----
    int wid = tid >> 6, l = tid & 63;
    int strip = wid & 3, half = wid >> 2;
    int c = l & 15, g = l >> 4;
    int r_base = r0 + strip * 16;

    half4v a1[4];
#pragma unroll
    for (int kk = 0; kk < 4; ++kk)
        a1[kk] = *reinterpret_cast<const half4v*>(&xs[strip * 16 + c][g * 4 + kk * 16]);

    f32x4 acc1[2];
#pragma unroll
    for (int nn = 0; nn < 2; ++nn) {
        int n = half * 2 + nn;
        const _Float16* bb = wt1 + (size_t)(n * 16 + c) * 64 + g * 4;
        half4v bf[4];
#pragma unroll
        for (int kk = 0; kk < 4; ++kk)
            bf[kk] = *reinterpret_cast<const half4v*>(bb + kk * 16);
        f32x4 z = {0.f, 0.f, 0.f, 0.f};
#pragma unroll
        for (int kk = 0; kk < 4; ++kk)
            z = __builtin_amdgcn_mfma_f32_16x16x16f16(a1[kk], bf[kk], z, 0, 0, 0);
        acc1[nn] = z;
    }
    __syncthreads();  // all waves done reading gathered xs (a1 loaded pre-GEMM)

    // bias + relu -> h1 transposed into xs (wave pair writes disjoint cols)
#pragma unroll
    for (int nn = 0; nn < 2; ++nn) {
        int n = half * 2 + nn;
        float bj = b1[n * 16 + c];
#pragma unroll
        for (int e = 0; e < 4; ++e) {
            float v = fmaxf(acc1[nn][e] + bj, 0.f);
            xs[strip * 16 + g * 4 + e][n * 16 + c] = (_Float16)v;
        }
    }
    __syncthreads();  // h1 complete (both halves) before A2 reads full rows

    half4v a2[4];
#pragma unroll
    for (int kk = 0; kk < 4; ++kk)
        a2[kk] = *reinterpret_cast<const half4v*>(&xs[strip * 16 + c][kk * 16 + g * 4]);

    f32x4 acc2[2];
#pragma unroll
    for (int nn = 0; nn < 2; ++nn) {
        int n = half * 2 + nn;
        const _Float16* bb = wt2 + (size_t)(n * 16 + c) * 64 + g * 4;
        half4v bf[4];
#pragma unroll
        for (int kk = 0; kk < 4; ++kk)
            bf[kk] = *reinterpret_cast<const half4v*>(bb + kk * 16);
        f32x4 z = {0.f, 0.f, 0.f, 0.f};
#pragma unroll
        for (int kk = 0; kk < 4; ++kk)
            z = __builtin_amdgcn_mfma_f32_16x16x16f16(a2[kk], bf[kk], z, 0, 0, 0);
        acc2[nn] = z;
    }
    __syncthreads();  // all waves done reading h1 from xs before overwrite

    // bias + relu -> RAW h into xs + masked BN stats
#pragma unroll
    for (int nn = 0; nn < 2; ++nn) {
        int n = half * 2 + nn;
        float bj = b2[n * 16 + c];
        float s = 0.f, q = 0.f;
#pragma unroll
        for (int e = 0; e < 4; ++e) {
            float v = fmaxf(acc2[nn][e] + bj, 0.f);
            xs[strip * 16 + g * 4 + e][n * 16 + c] = (_Float16)v;
            if (r_base + g * 4 + e < N_NODES) { s += v; q += v * v; }
        }
        atomicAdd(&sred[n * 16 + c], s);
        atomicAdd(&sred[64 + n * 16 + c], q);
    }
    __syncthreads();  // h complete before store

    // coalesced store: 8 waves x 8 rows, 8 lanes x 16 B per row
    {
        int row = wid * 8 + (l >> 3);
        int colh = (l & 7) * 8;
        int grow = r0 + row;
        if (grow < N_NODES) {
            float4 v = *reinterpret_cast<const float4*>(&xs[row][colh]);
            *reinterpret_cast<float4*>(reinterpret_cast<__half*>(hout) +
                                       (size_t)grow * 64 + colh) = v;
        }
    }

    if (tid < 128) atomicAdd(&stats[tid], sred[tid]);
}

// ---------------------------------------------------------------------------
// h' = relu(BN(h)) elementwise, fp16 -> fp16
__global__ __launch_bounds__(256) void bnrelu_k(const __half* hin,
                                                const float* __restrict__ stats,
                                                const float* __restrict__ g,
                                                const float* __restrict__ bt,
                                                __half* hout) {
    __shared__ float ssc[64], sof[64];
    int tid = threadIdx.x;
    if (tid < 64) {
        float mean = stats[tid] * (1.f / N_NODES);
        float var = stats[64 + tid] * (1.f / N_NODES) - mean * mean;
        float sc = g[tid] * rsqrtf(var + BN_EPS);
        ssc[tid] = sc;
        sof[tid] = bt[tid] - mean * sc;
    }
    __syncthreads();
    int gid = blockIdx.x * 256 + tid;      // one half8 (16 B) per thread
    if (gid >= N_NODES * 8) return;
    int c0 = (gid & 7) * 8;
    union { float4 f; __half2 h[4]; } u;
    u.f = reinterpret_cast<const float4*>(hin)[gid];
#pragma unroll
    for (int q = 0; q < 4; ++q) {
        float2 v = __half22float2(u.h[q]);
        v.x = fmaxf(fmaf(v.x, ssc[c0 + 2 * q], sof[c0 + 2 * q]), 0.f);
        v.y = fmaxf(fmaf(v.y, ssc[c0 + 2 * q + 1], sof[c0 + 2 * q + 1]), 0.f);
        u.h[q] = __float22half2_rn(v);
    }
    reinterpret_cast<float4*>(hout)[gid] = u.f;
}

// ---------------------------------------------------------------------------
// out[N x 16] = h' @ wl + bl   (h' fp16, already activated)
__global__ __launch_bounds__(256) void final_k(const __half* __restrict__ hin,
                                               const float* __restrict__ wl,
                                               const float* __restrict__ bl,
                                               float* __restrict__ out) {
    __shared__ float xs[64][68];
    __shared__ float wsh[64 * 16];
    __shared__ float bsh[16];
    int tid = threadIdx.x;
    int r0 = blockIdx.x * 64;

    reinterpret_cast<float4*>(wsh)[tid] = reinterpret_cast<const float4*>(wl)[tid];
    if (tid < 16) bsh[tid] = bl[tid];

    {
        int rr = tid >> 4, cg = tid & 15;
#pragma unroll
        for (int i = 0; i < 4; ++i) {
            int r = rr + i * 16;
            float4 v = make_float4(0.f, 0.f, 0.f, 0.f);
            if (r0 + r < N_NODES) {
                union { float2 f; __half2 h[2]; } u;
                u.f = reinterpret_cast<const float2*>(hin + (size_t)(r0 + r) * 64)[cg];
                float2 f0 = __half22float2(u.h[0]);
                float2 f1 = __half22float2(u.h[1]);
                v = make_float4(f0.x, f0.y, f1.x, f1.y);
            }
            xs[cg * 4 + 0][r] = v.x;
            xs[cg * 4 + 1][r] = v.y;
            xs[cg * 4 + 2][r] = v.z;
            xs[cg * 4 + 3][r] = v.w;
        }
    }
    __syncthreads();

    int tc = tid & 3, r = tid >> 2;
    int c = tc * 4;
    float acc0 = 0.f, acc1 = 0.f, acc2 = 0.f, acc3 = 0.f;
#pragma unroll 8
    for (int k = 0; k < 64; ++k) {
        float xv = xs[k][r];
        float4 wv = *reinterpret_cast<const float4*>(&wsh[k * 16 + c]);
        acc0 = fmaf(xv, wv.x, acc0);
        acc1 = fmaf(xv, wv.y, acc1);
        acc2 = fmaf(xv, wv.z, acc2);
        acc3 = fmaf(xv, wv.w, acc3);
    }
    int row = r0 + r;
    if (row < N_NODES) {
        float4 o = make_float4(acc0 + bsh[c], acc1 + bsh[c + 1], acc2 + bsh[c + 2], acc3 + bsh[c + 3]);
        *reinterpret_cast<float4*>(out + (size_t)row * 16 + c) = o;
    }
}

// ---------------------------------------------------------------------------
extern "C" void kernel_launch(void* const* d_in, const int* in_sizes, int n_in,
                              void* d_out, int out_size, void* d_ws, size_t ws_size,
                              hipStream_t stream) {
    const float* x = (const float*)d_in[0];
    const int* ei = (const int*)d_in[1];
    const int E = in_sizes[1] / 2;

    const float* eps[3] = {(const float*)d_in[2], (const float*)d_in[9], (const float*)d_in[16]};
    const float* w1[3]  = {(const float*)d_in[3], (const float*)d_in[10], (const float*)d_in[17]};
    const float* b1[3]  = {(const float*)d_in[4], (const float*)d_in[11], (const float*)d_in[18]};
    const float* w2[3]  = {(const float*)d_in[5], (const float*)d_in[12], (const float*)d_in[19]};
    const float* b2[3]  = {(const float*)d_in[6], (const float*)d_in[13], (const float*)d_in[20]};
    const float* g[3]   = {(const float*)d_in[7], (const float*)d_in[14], (const float*)d_in[21]};
    const float* bt[3]  = {(const float*)d_in[8], (const float*)d_in[15], (const float*)d_in[22]};
    const float* wl = (const float*)d_in[23];
    const float* bl = (const float*)d_in[24];

    // workspace layout (fp16 h buffers)
    __half* xh   = (__half*)d_ws;                           // N*64
    __half* ha   = xh + (size_t)N_NODES * 64;
    __half* hb   = ha + (size_t)N_NODES * 64;
    _Float16* wth = (_Float16*)(hb + (size_t)N_NODES * 64); // 6*4096
    float* stats = (float*)(wth + 6 * 4096);
    int* gcnt    = (int*)(stats + 384);
    int* cbase   = gcnt + NC;
    int* gcursor = cbase + (NC + 1);
    int* row_ptr = gcursor + NC;
    int* tail    = row_ptr + (N_NODES + 1);
    size_t used  = (size_t)((char*)tail - (char*)d_ws);

    int* csr_src = tail;                 // E ints, persists through all layers
    int* part;                           // E ints, build-only
    if (used + 2 * (size_t)E * 4 <= ws_size) {
        part = csr_src + E;
    } else {
        part = (int*)d_out;  // consumed by csrD_k before final_k writes d_out
    }

    const int n4 = N_NODES * 16;

    // ---- one-time: CSR build (coarse partition + per-bucket sort) + converts ----
    zero_misc_k<<<2, 256, 0, stream>>>(stats, gcnt);
    tofp16_k<<<(n4 + 255) / 256, 256, 0, stream>>>(x, xh, n4);
    wtr_k<<<6, 256, 0, stream>>>(w1[0], w2[0], w1[1], w2[1], w1[2], w2[2], wth);
    histC_k<<<PART_BLOCKS, 256, 0, stream>>>(ei, gcnt, E);
    scanC_k<<<1, 256, 0, stream>>>(gcnt, cbase, gcursor);
    partC_k<<<PART_BLOCKS, 256, 0, stream>>>(ei, gcursor, part, E);
    csrD_k<<<NC, 256, 0, stream>>>(part, cbase, row_ptr, csr_src);

    const int bnblk = (N_NODES * 8 + 255) / 256; // 3125

    // ---- 3 fused GIN layers ----
    layer_k<<<NBLK64, 512, 0, stream>>>(xh, row_ptr, csr_src, eps[0],
                                        wth + 0 * 4096, b1[0], wth + 1 * 4096, b2[0],
                                        ha, stats + 0);
    bnrelu_k<<<bnblk, 256, 0, stream>>>(ha, stats + 0, g[0], bt[0], ha);

    layer_k<<<NBLK64, 512, 0, stream>>>(ha, row_ptr, csr_src, eps[1],
                                        wth + 2 * 4096, b1[1], wth + 3 * 4096, b2[1],
                                        hb, stats + 128);
    bnrelu_k<<<bnblk, 256, 0, stream>>>(hb, stats + 128, g[1], bt[1], hb);

    layer_k<<<NBLK64, 512, 0, stream>>>(hb, row_ptr, csr_src, eps[2],
                                        wth + 4 * 4096, b1[2], wth + 5 * 4096, b2[2],
                                        ha, stats + 256);
    bnrelu_k<<<bnblk, 256, 0, stream>>>(ha, stats + 256, g[2], bt[2], ha);

    // ---- final linear ----
    final_k<<<(N_NODES + 63) / 64, 256, 0, stream>>>(ha, wl, bl, (float*)d_out);
}